// Round 15
// baseline (2308.738 us; speedup 1.0000x reference)
//
#include <hip/hip_runtime.h>

typedef short bf16x8 __attribute__((ext_vector_type(8)));
typedef float f32x4 __attribute__((ext_vector_type(4)));

static constexpr int kT = 512;
static constexpr int kN = 64;
static constexpr int kD = 1024;
static constexpr int kH = 1024;
static constexpr int kG = 4 * kH;  // 4096 gate columns

__device__ __forceinline__ unsigned short f2bf(float f) {
  unsigned u = __builtin_bit_cast(unsigned, f);
  return (unsigned short)((u + 0x7fffu + ((u >> 16) & 1u)) >> 16);  // RNE
}
__device__ __forceinline__ unsigned pack2(float a, float b) {
  return (unsigned)f2bf(a) | ((unsigned)f2bf(b) << 16);
}
__device__ __forceinline__ float fsigmoid(float v) {
  return __builtin_amdgcn_rcpf(1.0f + __expf(-v));
}
__device__ __forceinline__ float ftanh(float v) {
  return 1.0f - 2.0f * __builtin_amdgcn_rcpf(__expf(2.0f * v) + 1.0f);
}

// plain cached 16B load (issue-only; readiness via explicit counted vmcnt)
__device__ __forceinline__ bf16x8 gld16(unsigned long long a) {
  bf16x8 r;
  asm volatile("global_load_dwordx4 %0, %1, off" : "=v"(r) : "v"(a) : "memory");
  return r;
}

#define VMCNT(n) do { asm volatile("s_waitcnt vmcnt(" #n ")" ::: "memory"); \
                      __builtin_amdgcn_sched_barrier(0); } while (0)

// pre-pass: x fp32 -> bf16 (R2..R14-proven)
__global__ __launch_bounds__(256) void xconv(const float* __restrict__ x,
                                             unsigned short* __restrict__ xbf) {
  const int gid = blockIdx.x * 256 + threadIdx.x;
  const float4* x4 = (const float4*)x;
  uint4* o = (uint4*)xbf;
  for (int i = gid; i < (kN * kT * kD) / 8; i += 2048 * 256) {
    const float4 f0 = x4[2 * i];
    const float4 f1 = x4[2 * i + 1];
    uint4 p;
    p.x = pack2(f0.x, f0.y); p.y = pack2(f0.z, f0.w);
    p.z = pack2(f1.x, f1.y); p.w = pack2(f1.z, f1.w);
    o[i] = p;
  }
}

// =============== tagged exchange v2: rep-poll + one-shot fetch + atomic retry ===============
// 256 WGs x 256 threads, 1 WG/CU. WG (dom, ug): batch rows dom*16..+15, hidden
// cols ug*16..+15; Wx+Wh resident in VGPRs, K-split over 4 waves (R5..R14-proven).
// Exchange: each thread publishes (epoch<<16)|bf16(h) via __hip_atomic_store --
// NO drain, NO flags (producer-side serial RTs: zero). Consumer wave wv spins on
// 64 REPRESENTATIVE tags (1 dword/lane -- R10's proven poll shape/traffic), then
// one-shot raw dwordx4 loads of the full tagged fragment (proven one-shot-after-
// spin), tag-checks all 64 in registers, and re-loads rare stragglers via scalar
// __hip_atomic_load spin (proven primitive, bounded -> terminates). Correctness
// never depends on timing: any stale read fails the exact-match 16-bit tag.
// ABA-free: epochs 1..511 < 2^16; hTag memset each launch (in-graph, replay-safe).
template <bool PRE>
__global__ __launch_bounds__(256, 1)
void lstm_tag2(const float* __restrict__ x, const float* __restrict__ h0,
               const float* __restrict__ Wx, const float* __restrict__ Wh,
               const float* __restrict__ bias, float* __restrict__ out,
               unsigned* __restrict__ hTag, const unsigned short* __restrict__ xbf) {
  __shared__ float ps[2][16 * 320];  // double-buffered partials -> 1 sync/step

  const int tid = threadIdx.x;
  const int bx = blockIdx.x;
  const int dom = (bx & 7) >> 1;                 // 0..3
  const int ug = ((bx >> 3) << 1) | (bx & 1);    // 0..63
  const int wv = tid >> 6;                       // wave 0..3 (K-split)
  const int lane = tid & 63;

  // ---- weight fragments resident in VGPRs (R5..R14-proven layout)
  const int colc = ug * 16 + (lane & 15);
  const int krow = (lane >> 4) * 8;
  const int kb = wv * 256;
  bf16x8 wxf[4][8], whf[4][8];
#pragma unroll
  for (int ct = 0; ct < 4; ++ct) {
#pragma unroll
    for (int ks = 0; ks < 8; ++ks) {
      bf16x8 vx, vh;
#pragma unroll
      for (int e = 0; e < 8; ++e) {
        const size_t k = (size_t)(kb + ks * 32 + krow + e);
        vx[e] = (short)f2bf(Wx[k * kG + ct * kH + colc]);
        vh[e] = (short)f2bf(Wh[k * kG + ct * kH + colc]);
      }
      wxf[ct][ks] = vx;
      whf[ct][ks] = vh;
    }
  }

  // gate identity (each thread owns one h element -> publishes its own dword)
  const int n_l = tid >> 4;
  const int j_l = tid & 15;
  const int jg = ug * 16 + j_l;
  const float b_i = bias[jg];
  const float b_f = bias[kH + jg];
  const float b_o = bias[2 * kH + jg];
  const float b_g = bias[3 * kH + jg];
  float c = 0.0f;

  // A-frag / publish / poll identity
  const int arow = lane & 15;
  const int nrow = dom * 16 + arow;
  const unsigned long long xbase0 =
      (unsigned long long)nrow * kT * kD * 2 + (unsigned long long)(kb + krow) * 2;
  const unsigned pubeidx = (unsigned)((dom * 16 + n_l) * kH + jg);     // tagged dword
  const unsigned hrowelem = (unsigned)(nrow * kH + kb + krow);         // fragment base
  // rep for producer wave (ug' = wv*16+(lane&15), wv' = lane>>4): its first element
  const unsigned repidx = (unsigned)((dom * 16 + (lane >> 4) * 4) * kH +
                                     (wv * 16 + (lane & 15)) * 16);

  bf16x8 xfrag[8], hfrag[8];

  // ---- prologue: x(0) frags
  if (PRE) {
    const unsigned long long xb = (unsigned long long)xbf + xbase0;
#pragma unroll
    for (int ks = 0; ks < 8; ++ks) xfrag[ks] = gld16(xb + (unsigned)(ks * 64));
    VMCNT(0);
  } else {
    const float* xr = x + (size_t)nrow * kT * kD + (kb + krow);
#pragma unroll
    for (int ks = 0; ks < 8; ++ks) {
      const float4 f0 = *(const float4*)(xr + ks * 32);
      const float4 f1 = *(const float4*)(xr + ks * 32 + 4);
      bf16x8 v;
      v[0] = (short)f2bf(f0.x); v[1] = (short)f2bf(f0.y);
      v[2] = (short)f2bf(f0.z); v[3] = (short)f2bf(f0.w);
      v[4] = (short)f2bf(f1.x); v[5] = (short)f2bf(f1.y);
      v[6] = (short)f2bf(f1.z); v[7] = (short)f2bf(f1.w);
      xfrag[ks] = v;
    }
  }
  // acc = x-half of step 0
  f32x4 acc[4];
#pragma unroll
  for (int ct = 0; ct < 4; ++ct) acc[ct] = (f32x4){0.f, 0.f, 0.f, 0.f};
#pragma unroll
  for (int ks = 0; ks < 8; ++ks)
#pragma unroll
    for (int ct = 0; ct < 4; ++ct)
      acc[ct] = __builtin_amdgcn_mfma_f32_16x16x32_bf16(xfrag[ks], wxf[ct][ks], acc[ct], 0, 0, 0);
  // h(0) from h0 (fp32 -> bf16, compiler-managed loads/waits)
  {
    const float* hr = h0 + (size_t)nrow * kH + (kb + krow);
#pragma unroll
    for (int ks = 0; ks < 8; ++ks) {
      const float4 f0 = *(const float4*)(hr + ks * 32);
      const float4 f1 = *(const float4*)(hr + ks * 32 + 4);
      bf16x8 v;
      v[0] = (short)f2bf(f0.x); v[1] = (short)f2bf(f0.y);
      v[2] = (short)f2bf(f0.z); v[3] = (short)f2bf(f0.w);
      v[4] = (short)f2bf(f1.x); v[5] = (short)f2bf(f1.y);
      v[6] = (short)f2bf(f1.z); v[7] = (short)f2bf(f1.w);
      hfrag[ks] = v;
    }
  }
  VMCNT(0);  // clean ledger entering counted-land

  for (int t = 0; t < kT; ++t) {
    // ---- issue x(t+1) at loop TOP: full h-MFMA+gate latency hides it
    if (PRE && t < kT - 1) {
      const unsigned long long xb = (unsigned long long)xbf + xbase0 +
                                    (unsigned long long)(t + 1) * 2048u;
#pragma unroll
      for (int ks = 0; ks < 8; ++ks) xfrag[ks] = gld16(xb + (unsigned)(ks * 64));
    }

    // ---- h-half MFMAs (hfrag fully materialized at the previous edge)
#pragma unroll
    for (int ks = 0; ks < 8; ++ks)
#pragma unroll
      for (int ct = 0; ct < 4; ++ct)
        acc[ct] = __builtin_amdgcn_mfma_f32_16x16x32_bf16(hfrag[ks], whf[ct][ks], acc[ct], 0, 0, 0);

    // ---- cross-wave K reduction (double-buffered ps -> single sync per step)
    float* p = ps[t & 1];
#pragma unroll
    for (int ct = 0; ct < 4; ++ct)
      *(f32x4*)&p[(ct * 4 + wv) * 320 + (lane & 15) * 20 + (lane >> 4) * 4] = acc[ct];
    __syncthreads();

    float a4[4];
#pragma unroll
    for (int g = 0; g < 4; ++g) {
      a4[g] = p[(g * 4 + 0) * 320 + j_l * 20 + n_l]
            + p[(g * 4 + 1) * 320 + j_l * 20 + n_l]
            + p[(g * 4 + 2) * 320 + j_l * 20 + n_l]
            + p[(g * 4 + 3) * 320 + j_l * 20 + n_l];
    }
    const float gi = fsigmoid(a4[0] + b_i);
    const float gf = fsigmoid(a4[1] + b_f);
    const float go = fsigmoid(a4[2] + b_o);
    const float gg = ftanh(a4[3] + b_g);
    c = gf * c + gi * gg;
    const float hv = go * ftanh(c);

    if (t < kT - 1) {
      const unsigned tgt = (unsigned)(t + 1);
      unsigned* tbuf = hTag + (tgt & 1) * (unsigned)(kN * kH);

      // ---- retire x(t+1) loads (cheap: L3-resident, no store acks in queue)
      VMCNT(0);

      // ---- publish tagged h(t+1): 1 dword/thread, fire-and-forget
      __hip_atomic_store(tbuf + pubeidx, (tgt << 16) | (unsigned)f2bf(hv),
                         __ATOMIC_RELAXED, __HIP_MEMORY_SCOPE_AGENT);

      if (!PRE) {
        const float* xr = x + (size_t)nrow * kT * kD + (size_t)(t + 1) * kD + (kb + krow);
#pragma unroll
        for (int ks = 0; ks < 8; ++ks) {
          const float4 f0 = *(const float4*)(xr + ks * 32);
          const float4 f1 = *(const float4*)(xr + ks * 32 + 4);
          bf16x8 v;
          v[0] = (short)f2bf(f0.x); v[1] = (short)f2bf(f0.y);
          v[2] = (short)f2bf(f0.z); v[3] = (short)f2bf(f0.w);
          v[4] = (short)f2bf(f1.x); v[5] = (short)f2bf(f1.y);
          v[6] = (short)f2bf(f1.z); v[7] = (short)f2bf(f1.w);
          xfrag[ks] = v;
        }
      }
      // ---- x-half MFMAs for t+1 (fills the publish-transit window)
#pragma unroll
      for (int ct = 0; ct < 4; ++ct) acc[ct] = (f32x4){0.f, 0.f, 0.f, 0.f};
#pragma unroll
      for (int ks = 0; ks < 8; ++ks)
#pragma unroll
        for (int ct = 0; ct < 4; ++ct)
          acc[ct] = __builtin_amdgcn_mfma_f32_16x16x32_bf16(xfrag[ks], wxf[ct][ks], acc[ct], 0, 0, 0);

      // ---- rep-poll: 1 tagged dword/lane (proven spin primitive, R10 traffic)
      {
        const unsigned* repp = tbuf + repidx;
        for (;;) {
          const unsigned v = __hip_atomic_load(repp, __ATOMIC_RELAXED,
                                               __HIP_MEMORY_SCOPE_AGENT);
          if (__all((v >> 16) == tgt)) break;
          __builtin_amdgcn_s_sleep(1);
        }
      }
      __builtin_amdgcn_sched_barrier(0);

      // ---- one-shot raw fetch of the tagged fragment (16 x dwordx4)
      const unsigned* pb = tbuf + hrowelem;
      const unsigned long long hb = (unsigned long long)pb;
      uint4 tga[8], tgb[8];
#pragma unroll
      for (int ks = 0; ks < 8; ++ks) {
        asm volatile("global_load_dwordx4 %0, %1, off sc0 sc1"
                     : "=v"(tga[ks]) : "v"(hb + (unsigned)(ks * 128)) : "memory");
        asm volatile("global_load_dwordx4 %0, %1, off offset:16 sc0 sc1"
                     : "=v"(tgb[ks]) : "v"(hb + (unsigned)(ks * 128)) : "memory");
      }
      VMCNT(0);

      unsigned tgv[8][8];
#pragma unroll
      for (int ks = 0; ks < 8; ++ks) {
        tgv[ks][0] = tga[ks].x; tgv[ks][1] = tga[ks].y;
        tgv[ks][2] = tga[ks].z; tgv[ks][3] = tga[ks].w;
        tgv[ks][4] = tgb[ks].x; tgv[ks][5] = tgb[ks].y;
        tgv[ks][6] = tgb[ks].z; tgv[ks][7] = tgb[ks].w;
      }
      unsigned bad = 0;
#pragma unroll
      for (int ks = 0; ks < 8; ++ks)
#pragma unroll
        for (int e = 0; e < 8; ++e) bad |= (tgv[ks][e] >> 16) ^ tgt;

      if (!__all(bad == 0)) {
        // straggler path: re-load stale elements via proven atomic spin
        for (;;) {
          unsigned nb = 0;
#pragma unroll
          for (int ks = 0; ks < 8; ++ks)
#pragma unroll
            for (int e = 0; e < 8; ++e) {
              if ((tgv[ks][e] >> 16) != tgt)
                tgv[ks][e] = __hip_atomic_load(pb + ks * 32 + e, __ATOMIC_RELAXED,
                                               __HIP_MEMORY_SCOPE_AGENT);
              nb |= (tgv[ks][e] >> 16) ^ tgt;
            }
          if (__all(nb == 0)) break;
          __builtin_amdgcn_s_sleep(1);
        }
      }

      // ---- unpack (strip tags) -> hfrag for t+1
#pragma unroll
      for (int ks = 0; ks < 8; ++ks) {
        uint4 w;
        w.x = (tgv[ks][0] & 0xFFFFu) | (tgv[ks][1] << 16);
        w.y = (tgv[ks][2] & 0xFFFFu) | (tgv[ks][3] << 16);
        w.z = (tgv[ks][4] & 0xFFFFu) | (tgv[ks][5] << 16);
        w.w = (tgv[ks][6] & 0xFFFFu) | (tgv[ks][7] << 16);
        hfrag[ks] = __builtin_bit_cast(bf16x8, w);
      }

      // ---- out store LAST: its HBM ack retires across the next step
      __builtin_nontemporal_store(hv, &out[((size_t)(dom * 16 + n_l) * kT + t) * kH + jg]);
    } else {
      __builtin_nontemporal_store(hv, &out[((size_t)(dom * 16 + n_l) * kT + t) * kH + jg]);
    }
  }
}

// ======================= launch =======================
extern "C" void kernel_launch(void* const* d_in, const int* in_sizes, int n_in,
                              void* d_out, int out_size, void* d_ws, size_t ws_size,
                              hipStream_t stream) {
  (void)in_sizes; (void)n_in; (void)out_size;
  const float* x  = (const float*)d_in[0];
  const float* h0 = (const float*)d_in[1];
  const float* Wx = (const float*)d_in[2];
  const float* Wh = (const float*)d_in[3];
  const float* b  = (const float*)d_in[4];
  float* out = (float*)d_out;

  // ws: [0,512KB) tagged-h double buffer | [512KB,+64MB) bf16 x
  const size_t o_xbf = 524288;
  const size_t need_pre = o_xbf + (size_t)kN * kT * kD * 2;

  unsigned* hTag = (unsigned*)d_ws;
  unsigned short* xbf = (unsigned short*)((char*)d_ws + o_xbf);

  // reset ALL tags (in-graph, replay-safe: stale epochs would alias new ones)
  hipMemsetAsync(d_ws, 0, o_xbf, stream);

  if (ws_size >= need_pre) {
    hipLaunchKernelGGL(xconv, dim3(2048), dim3(256), 0, stream, x, xbf);
    hipLaunchKernelGGL(HIP_KERNEL_NAME(lstm_tag2<true>), dim3(256), dim3(256), 0, stream,
                       x, h0, Wx, Wh, b, out, hTag, xbf);
  } else {
    hipLaunchKernelGGL(HIP_KERNEL_NAME(lstm_tag2<false>), dim3(256), dim3(256), 0, stream,
                       x, h0, Wx, Wh, b, out, hTag, (const unsigned short*)nullptr);
  }
}

// Round 16
// 1991.178 us; speedup vs baseline: 1.1595x; 1.1595x over previous
//
#include <hip/hip_runtime.h>

typedef short bf16x8 __attribute__((ext_vector_type(8)));
typedef float f32x4 __attribute__((ext_vector_type(4)));

static constexpr int kT = 512;
static constexpr int kN = 64;
static constexpr int kD = 1024;
static constexpr int kH = 1024;
static constexpr int kG = 4 * kH;  // 4096 gate columns

__device__ __forceinline__ unsigned short f2bf(float f) {
  unsigned u = __builtin_bit_cast(unsigned, f);
  return (unsigned short)((u + 0x7fffu + ((u >> 16) & 1u)) >> 16);  // RNE
}
__device__ __forceinline__ unsigned pack2(float a, float b) {
  return (unsigned)f2bf(a) | ((unsigned)f2bf(b) << 16);
}
__device__ __forceinline__ float fsigmoid(float v) {
  return __builtin_amdgcn_rcpf(1.0f + __expf(-v));
}
__device__ __forceinline__ float ftanh(float v) {
  return 1.0f - 2.0f * __builtin_amdgcn_rcpf(__expf(2.0f * v) + 1.0f);
}

// one-shot coherent 16B load -- ONLY after a proven flag barrier (R4/5/7/10/14).
// NEVER spin on raw-asm loads (R6/8/9 livelocked); NEVER poll data (R11/R15).
__device__ __forceinline__ bf16x8 gld16_coh(unsigned long long a) {
  bf16x8 r;
  asm volatile("global_load_dwordx4 %0, %1, off sc0 sc1" : "=v"(r) : "v"(a) : "memory");
  return r;
}
// plain cached 16B load (issue-only; readiness via explicit counted vmcnt)
__device__ __forceinline__ bf16x8 gld16(unsigned long long a) {
  bf16x8 r;
  asm volatile("global_load_dwordx4 %0, %1, off" : "=v"(r) : "v"(a) : "memory");
  return r;
}

#define VMCNT(n) do { asm volatile("s_waitcnt vmcnt(" #n ")" ::: "memory"); \
                      __builtin_amdgcn_sched_barrier(0); } while (0)

// pre-pass: x fp32 -> bf16 (R2..R14-proven)
__global__ __launch_bounds__(256) void xconv(const float* __restrict__ x,
                                             unsigned short* __restrict__ xbf) {
  const int gid = blockIdx.x * 256 + threadIdx.x;
  const float4* x4 = (const float4*)x;
  uint4* o = (uint4*)xbf;
  for (int i = gid; i < (kN * kT * kD) / 8; i += 2048 * 256) {
    const float4 f0 = x4[2 * i];
    const float4 f1 = x4[2 * i + 1];
    uint4 p;
    p.x = pack2(f0.x, f0.y); p.y = pack2(f0.z, f0.w);
    p.z = pack2(f1.x, f1.y); p.w = pack2(f1.z, f1.w);
    o[i] = p;
  }
}

// ========== R14 structure + WG-granularity flags + single-poller (contention cut) ==========
// 256 WGs x 256 threads, 1 WG/CU. WG (dom, ug): batch rows dom*16..+15, hidden
// cols ug*16..+15; Wx+Wh resident in VGPRs, K-split over 4 waves.
// R16 deltas vs R14 (fabric-contention theory: 65K poll loads/iter drown the
// coherence point; cut poll traffic 4x and poller count 4x):
//  (1) WG flags (64/domain, DENSE): each wave, after its counted vmcnt(8)
//      publish-drain, bumps an LDS counter (R13-proven); the 4th-arriving wave
//      raises the single WG flag. Flag stores/step: 1024 -> 256.
//  (2) Only wave 0 polls (64 dense dwords, 1/lane -> ~2-line coalesced gather);
//      waves 1..3 spin on an LDS release word (zero fabric traffic).
//  All cross-WG primitives and the ABA induction are unchanged from R10/R14:
//  WG flag(t+1) => all 4 waves drained their publish => they finished the
//  t-1-edge h reads => overwriting h(t-1)'s slot is safe.
template <bool PRE>
__global__ __launch_bounds__(256, 1)
void lstm_fg3(const float* __restrict__ x, const float* __restrict__ h0,
              const float* __restrict__ Wx, const float* __restrict__ Wh,
              const float* __restrict__ bias, float* __restrict__ out,
              unsigned short* __restrict__ hbuf, unsigned* __restrict__ flags,
              const unsigned short* __restrict__ xbf) {
  __shared__ float ps[2][16 * 320];  // double-buffered partials -> 1 sync/step
  __shared__ unsigned wgcnt;         // monotonic wave-arrival counter (R13-proven)
  __shared__ unsigned rel;           // monotonic LDS release word

  const int tid = threadIdx.x;
  const int bx = blockIdx.x;
  const int dom = (bx & 7) >> 1;                 // 0..3
  const int ug = ((bx >> 3) << 1) | (bx & 1);    // 0..63
  const int wv = tid >> 6;                       // wave 0..3 (K-split)
  const int lane = tid & 63;

  if (tid == 0) { wgcnt = 0u; rel = 0u; }  // ordered before use by t=0 ps-sync

  // ---- weight fragments resident in VGPRs (R5..R14-proven layout)
  const int colc = ug * 16 + (lane & 15);
  const int krow = (lane >> 4) * 8;
  const int kb = wv * 256;
  bf16x8 wxf[4][8], whf[4][8];
#pragma unroll
  for (int ct = 0; ct < 4; ++ct) {
#pragma unroll
    for (int ks = 0; ks < 8; ++ks) {
      bf16x8 vx, vh;
#pragma unroll
      for (int e = 0; e < 8; ++e) {
        const size_t k = (size_t)(kb + ks * 32 + krow + e);
        vx[e] = (short)f2bf(Wx[k * kG + ct * kH + colc]);
        vh[e] = (short)f2bf(Wh[k * kG + ct * kH + colc]);
      }
      wxf[ct][ks] = vx;
      whf[ct][ks] = vh;
    }
  }

  // gate identity
  const int n_l = tid >> 4;
  const int j_l = tid & 15;
  const int jg = ug * 16 + j_l;
  const float b_i = bias[jg];
  const float b_f = bias[kH + jg];
  const float b_o = bias[2 * kH + jg];
  const float b_g = bias[3 * kH + jg];
  float c = 0.0f;

  // A-frag / publish identity
  const int arow = lane & 15;
  const int nrow = dom * 16 + arow;
  const unsigned long long xbase0 =
      (unsigned long long)nrow * kT * kD * 2 + (unsigned long long)(kb + krow) * 2;
  const unsigned long long hbase0 =
      (unsigned long long)nrow * kH * 2 + (unsigned long long)(kb + krow) * 2;
  const unsigned pubeidx = (unsigned)((dom * 16 + n_l) * kH + jg);

  // flag plumbing: ONE dense flag per WG; wave 0 polls lane -> WG `lane`
  unsigned* myflag = flags + (dom * 64 + ug);
  unsigned* pollp = flags + (dom * 64 + lane);

  bf16x8 xfrag[8], hfrag[8];

  // ---- prologue: x(0) frags
  if (PRE) {
    const unsigned long long xb = (unsigned long long)xbf + xbase0;
#pragma unroll
    for (int ks = 0; ks < 8; ++ks) xfrag[ks] = gld16(xb + (unsigned)(ks * 64));
    VMCNT(0);
  } else {
    const float* xr = x + (size_t)nrow * kT * kD + (kb + krow);
#pragma unroll
    for (int ks = 0; ks < 8; ++ks) {
      const float4 f0 = *(const float4*)(xr + ks * 32);
      const float4 f1 = *(const float4*)(xr + ks * 32 + 4);
      bf16x8 v;
      v[0] = (short)f2bf(f0.x); v[1] = (short)f2bf(f0.y);
      v[2] = (short)f2bf(f0.z); v[3] = (short)f2bf(f0.w);
      v[4] = (short)f2bf(f1.x); v[5] = (short)f2bf(f1.y);
      v[6] = (short)f2bf(f1.z); v[7] = (short)f2bf(f1.w);
      xfrag[ks] = v;
    }
  }
  // x-half of step 0
  f32x4 acc[4];
#pragma unroll
  for (int ct = 0; ct < 4; ++ct) acc[ct] = (f32x4){0.f, 0.f, 0.f, 0.f};
#pragma unroll
  for (int ks = 0; ks < 8; ++ks)
#pragma unroll
    for (int ct = 0; ct < 4; ++ct)
      acc[ct] = __builtin_amdgcn_mfma_f32_16x16x32_bf16(xfrag[ks], wxf[ct][ks], acc[ct], 0, 0, 0);
  // h(0) from h0 (fp32 -> bf16, compiler-managed loads/waits)
  {
    const float* hr = h0 + (size_t)nrow * kH + (kb + krow);
#pragma unroll
    for (int ks = 0; ks < 8; ++ks) {
      const float4 f0 = *(const float4*)(hr + ks * 32);
      const float4 f1 = *(const float4*)(hr + ks * 32 + 4);
      bf16x8 v;
      v[0] = (short)f2bf(f0.x); v[1] = (short)f2bf(f0.y);
      v[2] = (short)f2bf(f0.z); v[3] = (short)f2bf(f0.w);
      v[4] = (short)f2bf(f1.x); v[5] = (short)f2bf(f1.y);
      v[6] = (short)f2bf(f1.z); v[7] = (short)f2bf(f1.w);
      hfrag[ks] = v;
    }
  }
  VMCNT(0);  // zero the vmcnt ledger before entering counted-land

  for (int t = 0; t < kT; ++t) {
    // ---- h-half MFMAs; ledger = [out(1), h(8)] for t>0 (0 at t=0: trivial)
    VMCNT(4);   // retires {out, h0..h3}
#pragma unroll
    for (int ks = 0; ks < 4; ++ks)
#pragma unroll
      for (int ct = 0; ct < 4; ++ct)
        acc[ct] = __builtin_amdgcn_mfma_f32_16x16x32_bf16(hfrag[ks], whf[ct][ks], acc[ct], 0, 0, 0);
    VMCNT(0);   // retires {h4..h7}
#pragma unroll
    for (int ks = 4; ks < 8; ++ks)
#pragma unroll
      for (int ct = 0; ct < 4; ++ct)
        acc[ct] = __builtin_amdgcn_mfma_f32_16x16x32_bf16(hfrag[ks], whf[ct][ks], acc[ct], 0, 0, 0);

    // ---- cross-wave K reduction (double-buffered ps -> single sync per step)
    float* p = ps[t & 1];
#pragma unroll
    for (int ct = 0; ct < 4; ++ct)
      *(f32x4*)&p[(ct * 4 + wv) * 320 + (lane & 15) * 20 + (lane >> 4) * 4] = acc[ct];
    __syncthreads();

    float a4[4];
#pragma unroll
    for (int g = 0; g < 4; ++g) {
      a4[g] = p[(g * 4 + 0) * 320 + j_l * 20 + n_l]
            + p[(g * 4 + 1) * 320 + j_l * 20 + n_l]
            + p[(g * 4 + 2) * 320 + j_l * 20 + n_l]
            + p[(g * 4 + 3) * 320 + j_l * 20 + n_l];
    }
    const float gi = fsigmoid(a4[0] + b_i);
    const float gf = fsigmoid(a4[1] + b_f);
    const float go = fsigmoid(a4[2] + b_o);
    const float gg = ftanh(a4[3] + b_g);
    c = gf * c + gi * gg;
    const float hv = go * ftanh(c);

    if (t < kT - 1) {
      const unsigned tgt = (unsigned)(t + 1);
      const unsigned buf1 = tgt & 1;
      const unsigned mybf = (unsigned)f2bf(hv);
      const unsigned up = (unsigned)__shfl_xor((int)mybf, 1);

      if (PRE) {
        // publish -> x issue -> vmcnt(8): publish acked, x still in flight (R14)
        if ((j_l & 1) == 0) {
          __hip_atomic_store((unsigned*)(hbuf + buf1 * (kN * kH) + pubeidx),
                             mybf | (up << 16), __ATOMIC_RELAXED, __HIP_MEMORY_SCOPE_AGENT);
        }
        const unsigned long long xb = (unsigned long long)xbf + xbase0 +
                                      (unsigned long long)(t + 1) * 2048u;
#pragma unroll
        for (int ks = 0; ks < 8; ++ks) xfrag[ks] = gld16(xb + (unsigned)(ks * 64));
        VMCNT(8);   // ledger [pub, x*8] -> retires pub only
        // WG flag: 4th-arriving wave raises it (LDS atomic, R13-proven)
        if (lane == 0) {
          const unsigned old = atomicAdd(&wgcnt, 1u);
          if (old == 4u * (unsigned)t + 3u)
            __hip_atomic_store(myflag, tgt, __ATOMIC_RELAXED, __HIP_MEMORY_SCOPE_AGENT);
        }
        VMCNT(0);   // x ready (pub already retired)
      } else {
        if ((j_l & 1) == 0) {
          __hip_atomic_store((unsigned*)(hbuf + buf1 * (kN * kH) + pubeidx),
                             mybf | (up << 16), __ATOMIC_RELAXED, __HIP_MEMORY_SCOPE_AGENT);
        }
        VMCNT(0);
        if (lane == 0) {
          const unsigned old = atomicAdd(&wgcnt, 1u);
          if (old == 4u * (unsigned)t + 3u)
            __hip_atomic_store(myflag, tgt, __ATOMIC_RELAXED, __HIP_MEMORY_SCOPE_AGENT);
        }
        const float* xr = x + (size_t)nrow * kT * kD + (size_t)(t + 1) * kD + (kb + krow);
#pragma unroll
        for (int ks = 0; ks < 8; ++ks) {
          const float4 f0 = *(const float4*)(xr + ks * 32);
          const float4 f1 = *(const float4*)(xr + ks * 32 + 4);
          bf16x8 v;
          v[0] = (short)f2bf(f0.x); v[1] = (short)f2bf(f0.y);
          v[2] = (short)f2bf(f0.z); v[3] = (short)f2bf(f0.w);
          v[4] = (short)f2bf(f1.x); v[5] = (short)f2bf(f1.y);
          v[6] = (short)f2bf(f1.z); v[7] = (short)f2bf(f1.w);
          xfrag[ks] = v;
        }
      }

      // ---- x-half MFMAs for t+1 (fills the flag-transit window)
#pragma unroll
      for (int ct = 0; ct < 4; ++ct) acc[ct] = (f32x4){0.f, 0.f, 0.f, 0.f};
#pragma unroll
      for (int ks = 0; ks < 8; ++ks)
#pragma unroll
        for (int ct = 0; ct < 4; ++ct)
          acc[ct] = __builtin_amdgcn_mfma_f32_16x16x32_bf16(xfrag[ks], wxf[ct][ks], acc[ct], 0, 0, 0);

      // out-store: ack retires under poll + h-load + next step edge (R14)
      __builtin_amdgcn_sched_barrier(0);
      __builtin_nontemporal_store(hv, &out[((size_t)(dom * 16 + n_l) * kT + t) * kH + jg]);

      // ---- single-poller barrier: wave 0 polls 64 dense WG flags (1/lane,
      //      coalesced); waves 1..3 spin on the LDS release word (no fabric)
      if (wv == 0) {
        for (;;) {
          const unsigned v = __hip_atomic_load(pollp, __ATOMIC_RELAXED,
                                               __HIP_MEMORY_SCOPE_AGENT);
          if (__all((int)v >= (int)tgt)) break;
          __builtin_amdgcn_s_sleep(1);
        }
        __hip_atomic_store(&rel, tgt, __ATOMIC_RELAXED, __HIP_MEMORY_SCOPE_WORKGROUP);
      } else {
        while (__hip_atomic_load(&rel, __ATOMIC_RELAXED, __HIP_MEMORY_SCOPE_WORKGROUP) < tgt)
          __builtin_amdgcn_s_sleep(1);
      }
      __builtin_amdgcn_sched_barrier(0);

      // ---- one-shot coherent h(t+1) loads (proven post-barrier pattern)
      const unsigned long long hb = (unsigned long long)hbuf +
                                    (unsigned long long)buf1 * (kN * kH * 2) + hbase0;
#pragma unroll
      for (int ks = 0; ks < 8; ++ks) hfrag[ks] = gld16_coh(hb + (unsigned)(ks * 64));
    } else {
      __builtin_nontemporal_store(hv, &out[((size_t)(dom * 16 + n_l) * kT + t) * kH + jg]);
    }
  }
}

// ======================= launch =======================
extern "C" void kernel_launch(void* const* d_in, const int* in_sizes, int n_in,
                              void* d_out, int out_size, void* d_ws, size_t ws_size,
                              hipStream_t stream) {
  (void)in_sizes; (void)n_in; (void)out_size;
  const float* x  = (const float*)d_in[0];
  const float* h0 = (const float*)d_in[1];
  const float* Wx = (const float*)d_in[2];
  const float* Wh = (const float*)d_in[3];
  const float* b  = (const float*)d_in[4];
  float* out = (float*)d_out;

  // ws: [0,4KB) dense WG flags | [4KB,+256KB) h double buffer | then bf16 x
  const size_t o_hbuf = 4096;
  const size_t o_xbf = o_hbuf + 262144;
  const size_t need_pre = o_xbf + (size_t)kN * kT * kD * 2;

  unsigned* flags = (unsigned*)d_ws;
  unsigned short* hbuf = (unsigned short*)((char*)d_ws + o_hbuf);
  unsigned short* xbf = (unsigned short*)((char*)d_ws + o_xbf);

  hipMemsetAsync(d_ws, 0, 4096, stream);  // reset flags (in-graph, replay-safe)

  if (ws_size >= need_pre) {
    hipLaunchKernelGGL(xconv, dim3(2048), dim3(256), 0, stream, x, xbf);
    hipLaunchKernelGGL(HIP_KERNEL_NAME(lstm_fg3<true>), dim3(256), dim3(256), 0, stream,
                       x, h0, Wx, Wh, b, out, hbuf, flags, xbf);
  } else {
    hipLaunchKernelGGL(HIP_KERNEL_NAME(lstm_fg3<false>), dim3(256), dim3(256), 0, stream,
                       x, h0, Wx, Wh, b, out, hbuf, flags,
                       (const unsigned short*)nullptr);
  }
}